// Round 16
// baseline (242.471 us; speedup 1.0000x reference)
//
#include <hip/hip_runtime.h>

typedef __bf16 bf16x8 __attribute__((ext_vector_type(8)));
typedef __bf16 bf16x4 __attribute__((ext_vector_type(4)));
typedef float f32x4 __attribute__((ext_vector_type(4)));
typedef float f32x16 __attribute__((ext_vector_type(16)));

#define BB 4
#define SS 1024
#define DD 1024
#define HH 16
#define DHH 64
#define FFN 4096

__device__ __forceinline__ void gload_lds16(const void* g, void* lds) {
  __builtin_amdgcn_global_load_lds(
      (const __attribute__((address_space(1))) unsigned int*)g,
      (__attribute__((address_space(3))) unsigned int*)lds, 16, 0, 0);
}

// One-shot fp32->bf16 conversion of all inputs. Chunk = 8 elems, 2097152 chunks.
__global__ __launch_bounds__(256) void cvt_all_kernel(
    const float* __restrict__ x, const float* __restrict__ wq, const float* __restrict__ wk,
    const float* __restrict__ wv, const float* __restrict__ wo, const float* __restrict__ w1,
    const float* __restrict__ w2, __bf16* __restrict__ xb, __bf16* __restrict__ wqkvb,
    __bf16* __restrict__ wob, __bf16* __restrict__ w1b, __bf16* __restrict__ w2b)
{
  int i = blockIdx.x * 256 + threadIdx.x;   // chunk index
  const float* src; __bf16* dst; int off;
  if (i < 524288)       { src = x;  dst = xb;              off = i; }
  else if (i < 655360)  { src = wq; dst = wqkvb;           off = i - 524288; }
  else if (i < 786432)  { src = wk; dst = wqkvb + 1048576; off = i - 655360; }
  else if (i < 917504)  { src = wv; dst = wqkvb + 2097152; off = i - 786432; }
  else if (i < 1048576) { src = wo; dst = wob;             off = i - 917504; }
  else if (i < 1572864) { src = w1; dst = w1b;             off = i - 1048576; }
  else                  { src = w2; dst = w2b;             off = i - 1572864; }
  float4 a = *(const float4*)(src + off * 8);
  float4 b = *(const float4*)(src + off * 8 + 4);
  bf16x8 v;
  v[0] = (__bf16)a.x; v[1] = (__bf16)a.y; v[2] = (__bf16)a.z; v[3] = (__bf16)a.w;
  v[4] = (__bf16)b.x; v[5] = (__bf16)b.y; v[6] = (__bf16)b.z; v[7] = (__bf16)b.w;
  *(bf16x8*)(dst + off * 8) = v;
}

// ---------------------------------------------------------------------------
// WIDE 2-phase GEMM: BM=128 x BN=256, BK=32, 512 thr / 8 waves (2M x 4N),
// wave tile 64x64 (identical schedule/fragments/VGPR to proven 128^2 kernel).
// Staged bytes per block-iter: 24 KB for 2.1 MFLOP (vs 16 KB / 1.05 MFLOP)
// -> 25% fewer DMA bytes per FLOP, half the weight-panel DMA per FLOP.
// LDS 48 KB -> 3 blocks/CU.
// MODE 3: out bf16 = relu(acc+bias)
// MODE 4: fused QKV (N=3072): Q,K -> [B,H,S,DH]; V -> [B,H,DH,S] (via res ptr)
// MODE 5: split-K partial f32 via blockIdx.z
// ---------------------------------------------------------------------------
template<int MODE>
__global__ __launch_bounds__(512, 2) void gemm_wide(
    const __bf16* __restrict__ A, const __bf16* __restrict__ Bw,
    const float* __restrict__ bias, const float* __restrict__ bias1, const float* __restrict__ bias2,
    const float* __restrict__ res, void* __restrict__ outp, void* __restrict__ out1,
    int M, int N, int K, int kLen, float scale)
{
  __shared__ __bf16 As[2][128 * 32];   // 8 KB per buffer
  __shared__ __bf16 Bs[2][256 * 32];   // 16 KB per buffer
  const int tid = threadIdx.x;
  const int wid = tid >> 6;
  const int lane = tid & 63;
  const int lr = lane & 15;
  const int lg = lane >> 4;

  // XCD-chunked linear swizzle (proven)
  const int gx = gridDim.x;
  const int nwg = gx * gridDim.y;
  const int wg = blockIdx.y * gx + blockIdx.x;
  const int swz = (wg & 7) * (nwg >> 3) + (wg >> 3);
  const int bm = (swz / gx) * 128;
  const int bn = (swz % gx) * 256;

  const int wm = (wid >> 2) * 64;      // 0 or 64
  const int wn = (wid & 3) * 64;       // 0,64,128,192

  int kBeg = 0, nk = K >> 5;
  if constexpr (MODE == 5) { kBeg = blockIdx.z * kLen; nk = kLen >> 5; }

  // staging (linear): thread t covers 16B slot t of each 8KB region
  const int sra = tid >> 2;                 // row 0..127
  const int sca = (tid & 3) << 3;           // element col within 32
  const __bf16* gA  = A + (size_t)(bm + sra) * K + kBeg + sca;
  const __bf16* gB0 = Bw + (size_t)(bn + sra) * K + kBeg + sca;
  const __bf16* gB1 = Bw + (size_t)(bn + 128 + sra) * K + kBeg + sca;
  char* lA = (char*)&As[0][0] + wid * 1024;   // wave-uniform base (+lane*16 by HW)
  char* lB = (char*)&Bs[0][0] + wid * 1024;

  f32x4 acc[4][4] = {};

#define STAGE(buf, kk) do { \
    gload_lds16(gA + (kk), lA + (buf) * 8192); \
    gload_lds16(gB0 + (kk), lB + (buf) * 16384); \
    gload_lds16(gB1 + (kk), lB + (buf) * 16384 + 8192); \
  } while (0)

  STAGE(0, 0);
  __syncthreads();
  for (int t = 0; t < nk; ++t) {
    const int cur = t & 1;
    if (t + 1 < nk) STAGE(cur ^ 1, (t + 1) << 5);
    bf16x8 af[4], bv[4];
#pragma unroll
    for (int i = 0; i < 4; ++i)
      af[i] = *(const bf16x8*)&As[cur][(wm + i * 16 + lr) * 32 + lg * 8];
#pragma unroll
    for (int i = 0; i < 4; ++i)
      bv[i] = *(const bf16x8*)&Bs[cur][(wn + i * 16 + lr) * 32 + lg * 8];
#pragma unroll
    for (int i = 0; i < 4; ++i)
#pragma unroll
      for (int j = 0; j < 4; ++j)
        acc[i][j] = __builtin_amdgcn_mfma_f32_16x16x32_bf16(af[i], bv[j], acc[i][j], 0, 0, 0);
    __syncthreads();
  }
#undef STAGE

  // epilogue: C/D layout col=lane&15, row=(lane>>4)*4+r  [m89-verified]
#pragma unroll
  for (int i = 0; i < 4; ++i) {
#pragma unroll
    for (int j = 0; j < 4; ++j) {
#pragma unroll
      for (int r = 0; r < 4; ++r) {
        int row = bm + wm + i * 16 + lg * 4 + r;
        int col = bn + wn + j * 16 + lr;
        float v = acc[i][j][r];
        if constexpr (MODE == 3) {
          float t2 = v + bias[col];
          ((__bf16*)outp)[(size_t)row * N + col] = (__bf16)fmaxf(t2, 0.f);
        } else if constexpr (MODE == 4) {
          int region = col >> 10;        // 0=Q 1=K 2=V (uniform per block: 256 | 1024)
          int col_ = col & 1023;
          int b_ = row >> 10, s_ = row & 1023;
          int h_ = col_ >> 6, d_ = col_ & 63;
          if (region == 0) {
            float v2 = (v + bias[col_]) * scale;   // log2e/8
            ((__bf16*)outp)[(((size_t)(b_ * HH + h_) * SS) + s_) * DHH + d_] = (__bf16)v2;
          } else if (region == 1) {
            float v2 = v + bias1[col_];
            ((__bf16*)out1)[(((size_t)(b_ * HH + h_) * SS) + s_) * DHH + d_] = (__bf16)v2;
          } else {
            float v2 = v + bias2[col_];
            ((__bf16*)res)[(((size_t)(b_ * HH + h_) * DHH) + d_) * SS + s_] = (__bf16)v2;
          }
        } else if constexpr (MODE == 5) {
          float* dst = blockIdx.z ? (float*)out1 : (float*)outp;
          dst[(size_t)row * N + col] = v;
        }
      }
    }
  }
}

// 128x128 2-phase GEMM (r12-proven), kept for WO only.
// MODE 6: out bf16 = acc+bias+res(f32)
template<int MODE>
__global__ __launch_bounds__(256, 2) void gemm_wo(
    const __bf16* __restrict__ A, const __bf16* __restrict__ Bw,
    const float* __restrict__ bias, const float* __restrict__ res,
    void* __restrict__ outp, int M, int N, int K)
{
  __shared__ __bf16 As[2][128 * 32];
  __shared__ __bf16 Bs[2][128 * 32];
  const int tid = threadIdx.x;
  const int wid = tid >> 6;
  const int lane = tid & 63;
  const int lr = lane & 15;
  const int lg = lane >> 4;

  const int gx = gridDim.x;
  const int nwg = gx * gridDim.y;
  const int wg = blockIdx.y * gx + blockIdx.x;
  const int swz = (wg & 7) * (nwg >> 3) + (wg >> 3);
  const int bm = (swz / gx) * 128;
  const int bn = (swz % gx) * 128;

  const int wm = (wid >> 1) * 64;
  const int wn = (wid & 1) * 64;

  const int nk = K >> 5;

  const int off = tid * 16;
  const int srow = off >> 6;
  const int scol = (off & 63) >> 1;
  const __bf16* gA0 = A + (size_t)(bm + srow) * K + scol;
  const __bf16* gA1 = A + (size_t)(bm + 64 + srow) * K + scol;
  const __bf16* gB0 = Bw + (size_t)(bn + srow) * K + scol;
  const __bf16* gB1 = Bw + (size_t)(bn + 64 + srow) * K + scol;
  char* lA = (char*)&As[0][0] + wid * 1024;
  char* lB = (char*)&Bs[0][0] + wid * 1024;

  f32x4 acc[4][4] = {};

#define STAGE(buf, kk) do { \
    gload_lds16(gA0 + (kk), lA + (buf) * 8192); \
    gload_lds16(gA1 + (kk), lA + (buf) * 8192 + 4096); \
    gload_lds16(gB0 + (kk), lB + (buf) * 8192); \
    gload_lds16(gB1 + (kk), lB + (buf) * 8192 + 4096); \
  } while (0)

  STAGE(0, 0);
  __syncthreads();
  for (int t = 0; t < nk; ++t) {
    const int cur = t & 1;
    if (t + 1 < nk) STAGE(cur ^ 1, (t + 1) << 5);
    bf16x8 af[4], bv[4];
#pragma unroll
    for (int i = 0; i < 4; ++i)
      af[i] = *(const bf16x8*)&As[cur][(wm + i * 16 + lr) * 32 + lg * 8];
#pragma unroll
    for (int i = 0; i < 4; ++i)
      bv[i] = *(const bf16x8*)&Bs[cur][(wn + i * 16 + lr) * 32 + lg * 8];
#pragma unroll
    for (int i = 0; i < 4; ++i)
#pragma unroll
      for (int j = 0; j < 4; ++j)
        acc[i][j] = __builtin_amdgcn_mfma_f32_16x16x32_bf16(af[i], bv[j], acc[i][j], 0, 0, 0);
    __syncthreads();
  }
#undef STAGE

#pragma unroll
  for (int i = 0; i < 4; ++i) {
#pragma unroll
    for (int j = 0; j < 4; ++j) {
#pragma unroll
      for (int r = 0; r < 4; ++r) {
        int row = bm + wm + i * 16 + lg * 4 + r;
        int col = bn + wn + j * 16 + lr;
        float v = acc[i][j][r];
        if constexpr (MODE == 6) {
          size_t idx = (size_t)row * N + col;
          ((__bf16*)outp)[idx] = (__bf16)(v + bias[col] + res[idx]);
        }
      }
    }
  }
}

// Flash attention: LDS-staged double-buffered K/V, 32x32x16 MFMA,
// fixed-max softmax, XOR slot-swizzle.
__global__ __launch_bounds__(256, 2) void attn_kernel(
    const __bf16* __restrict__ q, const __bf16* __restrict__ k,
    const __bf16* __restrict__ vt, const int* __restrict__ mask,
    __bf16* __restrict__ ctx)
{
  const int nwg = gridDim.x;          // 512
  const int wg = blockIdx.x;
  const int swzb = (wg & 7) * (nwg >> 3) + (wg >> 3);
  const int bh = swzb >> 3;
  const int qb = (swzb & 7) << 7;
  const int b = bh >> 4;

  const int tid = threadIdx.x, wid = tid >> 6, lane = tid & 63;
  const int ln = lane & 31, hi = lane >> 5;

  __shared__ __bf16 Kt[2][64 * 64];
  __shared__ __bf16 Vt[2][64 * 64];
  __shared__ __bf16 Pt[4][32 * 64];
  __shared__ float mmulLds[SS];

  {
    const int* mrow = mask + b * SS;
    int c = tid * 4;
    float4 mm;
    mm.x = (float)(mrow[c + 0] != 0);
    mm.y = (float)(mrow[c + 1] != 0);
    mm.z = (float)(mrow[c + 2] != 0);
    mm.w = (float)(mrow[c + 3] != 0);
    ((float4*)mmulLds)[tid] = mm;
  }

  const __bf16* qh = q + (size_t)bh * SS * DHH;
  const __bf16* kh = k + (size_t)bh * SS * DHH;
  const __bf16* vh = vt + (size_t)bh * DHH * SS;

  const int qw = qb + wid * 32;
  bf16x8 qf[4];
#pragma unroll
  for (int s = 0; s < 4; ++s)
    qf[s] = *(const bf16x8*)&qh[(size_t)(qw + ln) * DHH + s * 16 + hi * 8];

  const int srow = tid >> 3;
  const int ps = tid & 7;
  const int sw0 = (srow ^ (srow >> 3)) & 7;
  const int r1 = srow + 32;
  const int sw1 = (r1 ^ (r1 >> 3)) & 7;
  const __bf16* kS0 = kh + (size_t)srow * DHH + ((ps ^ sw0) * 8);
  const __bf16* kS1 = kh + (size_t)r1 * DHH + ((ps ^ sw1) * 8);
  const __bf16* vS0 = vh + (size_t)srow * SS + ((ps ^ sw0) * 8);
  const __bf16* vS1 = vh + (size_t)r1 * SS + ((ps ^ sw1) * 8);

#define ASTAGE(bufi, kb_) do { \
    gload_lds16(kS0 + (size_t)(kb_) * DHH, (char*)&Kt[bufi][0] + wid * 1024); \
    gload_lds16(kS1 + (size_t)(kb_) * DHH, (char*)&Kt[bufi][0] + wid * 1024 + 4096); \
    gload_lds16(vS0 + (kb_), (char*)&Vt[bufi][0] + wid * 1024); \
    gload_lds16(vS1 + (kb_), (char*)&Vt[bufi][0] + wid * 1024 + 4096); \
  } while (0)

  char* Pw = (char*)&Pt[wid][0];
  const int swA = (ln ^ (ln >> 3)) & 7;
  const int swB = swA ^ 4;

  f32x16 o0 = {}, o1 = {};
  float l[16];
#pragma unroll
  for (int r = 0; r < 16; ++r) l[r] = 0.f;

  ASTAGE(0, 0);
  __syncthreads();

#pragma unroll 1
  for (int t = 0; t < SS / 64; ++t) {
    const int cur = t & 1;
    const int kb = t * 64;
    if (t + 1 < SS / 64) ASTAGE(cur ^ 1, kb + 64);

    const char* Kc = (const char*)&Kt[cur][0];
    const char* Vc = (const char*)&Vt[cur][0];

    f32x16 sc0 = {}, sc1 = {};
#pragma unroll
    for (int s = 0; s < 4; ++s) {
      bf16x8 kb0 = *(const bf16x8*)(Kc + ln * 128 + (((s * 2 + hi) ^ swA) << 4));
      bf16x8 kb1 = *(const bf16x8*)(Kc + (32 + ln) * 128 + (((s * 2 + hi) ^ swB) << 4));
      sc0 = __builtin_amdgcn_mfma_f32_32x32x16_bf16(qf[s], kb0, sc0, 0, 0, 0);
      sc1 = __builtin_amdgcn_mfma_f32_32x32x16_bf16(qf[s], kb1, sc1, 0, 0, 0);
    }

    float mm0 = mmulLds[kb + ln];
    float mm1 = mmulLds[kb + 32 + ln];
#pragma unroll
    for (int r = 0; r < 16; ++r) {
      float p0 = exp2f(sc0[r] - 23.0831207f) * mm0;
      float p1 = exp2f(sc1[r] - 23.0831207f) * mm1;
      l[r] += p0 + p1;
      int qrow = (r & 3) + 8 * (r >> 2) + 4 * hi;
      int swq = (qrow ^ (qrow >> 3)) & 7;
      *(__bf16*)(Pw + qrow * 128 + ((((ln >> 3) + 0) ^ swq) << 4) + (ln & 7) * 2) = (__bf16)p0;
      *(__bf16*)(Pw + qrow * 128 + ((((ln >> 3) + 4) ^ swq) << 4) + (ln & 7) * 2) = (__bf16)p1;
    }

#pragma unroll
    for (int ks = 0; ks < 4; ++ks) {
      bf16x8 pa = *(const bf16x8*)(Pw + ln * 128 + (((ks * 2 + hi) ^ swA) << 4));
      bf16x8 vb0 = *(const bf16x8*)(Vc + ln * 128 + (((ks * 2 + hi) ^ swA) << 4));
      bf16x8 vb1 = *(const bf16x8*)(Vc + (32 + ln) * 128 + (((ks * 2 + hi) ^ swB) << 4));
      o0 = __builtin_amdgcn_mfma_f32_32x32x16_bf16(pa, vb0, o0, 0, 0, 0);
      o1 = __builtin_amdgcn_mfma_f32_32x32x16_bf16(pa, vb1, o1, 0, 0, 0);
    }
    __syncthreads();
  }
#undef ASTAGE

#pragma unroll
  for (int r = 0; r < 16; ++r) {
#pragma unroll
    for (int off = 1; off < 32; off <<= 1) l[r] += __shfl_xor(l[r], off);
  }

#pragma unroll
  for (int r = 0; r < 16; ++r) {
    float inv = l[r] > 0.f ? 1.f / l[r] : 0.f;
    int qrow = (r & 3) + 8 * (r >> 2) + 4 * hi;
    size_t base = ((size_t)b * SS + qw + qrow) * DD + (size_t)(bh & 15) * DHH;
    ctx[base + ln] = (__bf16)(o0[r] * inv);
    ctx[base + 32 + ln] = (__bf16)(o1[r] * inv);
  }
}

// LayerNorm over D=1024, bf16 input, bf16 output only (tb doubles as LN2 residual)
__global__ __launch_bounds__(256) void ln_bf16_kernel(
    const __bf16* __restrict__ in, const float* __restrict__ g, const float* __restrict__ b,
    __bf16* __restrict__ out16)
{
  int row = blockIdx.x;
  int tid = threadIdx.x;
  int wid = tid >> 6, lane = tid & 63;
  bf16x4 raw = ((const bf16x4*)(in + (size_t)row * DD))[tid];
  float4 v;
  v.x = (float)raw[0]; v.y = (float)raw[1]; v.z = (float)raw[2]; v.w = (float)raw[3];
  float s = v.x + v.y + v.z + v.w;
  float sq = v.x * v.x + v.y * v.y + v.z * v.z + v.w * v.w;
#pragma unroll
  for (int o = 1; o < 64; o <<= 1) { s += __shfl_xor(s, o); sq += __shfl_xor(sq, o); }
  __shared__ float red[8];
  if (lane == 0) { red[wid] = s; red[4 + wid] = sq; }
  __syncthreads();
  s = red[0] + red[1] + red[2] + red[3];
  sq = red[4] + red[5] + red[6] + red[7];
  float mean = s * (1.f / DD);
  float var = sq * (1.f / DD) - mean * mean;
  float rstd = rsqrtf(var + 1e-5f);
  float4 gg = ((const float4*)g)[tid];
  float4 bb = ((const float4*)b)[tid];
  bf16x4 w;
  w[0] = (__bf16)((v.x - mean) * rstd * gg.x + bb.x);
  w[1] = (__bf16)((v.y - mean) * rstd * gg.y + bb.y);
  w[2] = (__bf16)((v.z - mean) * rstd * gg.z + bb.z);
  w[3] = (__bf16)((v.w - mean) * rstd * gg.w + bb.w);
  *(bf16x4*)(out16 + (size_t)row * DD + tid * 4) = w;
}

// LN2 fused with split-K reduce: v = p0 + p1 + bias(b2) + res(tb bf16); LN; mask
__global__ __launch_bounds__(256) void ln2_fused_kernel(
    const float* __restrict__ p0, const float* __restrict__ p1, const float* __restrict__ bias,
    const __bf16* __restrict__ res, const float* __restrict__ g, const float* __restrict__ b,
    const int* __restrict__ mask, float* __restrict__ out)
{
  int row = blockIdx.x;
  int tid = threadIdx.x;
  int wid = tid >> 6, lane = tid & 63;
  size_t base = (size_t)row * DD;
  float4 a0 = ((const float4*)(p0 + base))[tid];
  float4 a1 = ((const float4*)(p1 + base))[tid];
  bf16x4 rw = ((const bf16x4*)(res + base))[tid];
  float4 bs = ((const float4*)bias)[tid];
  float4 v;
  v.x = a0.x + a1.x + (float)rw[0] + bs.x;
  v.y = a0.y + a1.y + (float)rw[1] + bs.y;
  v.z = a0.z + a1.z + (float)rw[2] + bs.z;
  v.w = a0.w + a1.w + (float)rw[3] + bs.w;
  float s = v.x + v.y + v.z + v.w;
  float sq = v.x * v.x + v.y * v.y + v.z * v.z + v.w * v.w;
#pragma unroll
  for (int o = 1; o < 64; o <<= 1) { s += __shfl_xor(s, o); sq += __shfl_xor(sq, o); }
  __shared__ float red[8];
  if (lane == 0) { red[wid] = s; red[4 + wid] = sq; }
  __syncthreads();
  s = red[0] + red[1] + red[2] + red[3];
  sq = red[4] + red[5] + red[6] + red[7];
  float mean = s * (1.f / DD);
  float var = sq * (1.f / DD) - mean * mean;
  float rstd = rsqrtf(var + 1e-5f);
  float4 gg = ((const float4*)g)[tid];
  float4 bb = ((const float4*)b)[tid];
  float mk = (float)mask[row];
  float4 o;
  o.x = ((v.x - mean) * rstd * gg.x + bb.x) * mk;
  o.y = ((v.y - mean) * rstd * gg.y + bb.y) * mk;
  o.z = ((v.z - mean) * rstd * gg.z + bb.z) * mk;
  o.w = ((v.w - mean) * rstd * gg.w + bb.w) * mk;
  ((float4*)(out + base))[tid] = o;
}

extern "C" void kernel_launch(void* const* d_in, const int* in_sizes, int n_in,
                              void* d_out, int out_size, void* d_ws, size_t ws_size,
                              hipStream_t stream) {
  const float* x    = (const float*)d_in[0];
  const int*  mask  = (const int*)d_in[1];
  const float* wq   = (const float*)d_in[2];
  const float* bq   = (const float*)d_in[3];
  const float* wk   = (const float*)d_in[4];
  const float* bk   = (const float*)d_in[5];
  const float* wv   = (const float*)d_in[6];
  const float* bv   = (const float*)d_in[7];
  const float* wo   = (const float*)d_in[8];
  const float* bo   = (const float*)d_in[9];
  const float* ln1g = (const float*)d_in[10];
  const float* ln1b = (const float*)d_in[11];
  const float* w1   = (const float*)d_in[12];
  const float* b1   = (const float*)d_in[13];
  const float* w2   = (const float*)d_in[14];
  const float* b2   = (const float*)d_in[15];
  const float* ln2g = (const float*)d_in[16];
  const float* ln2b = (const float*)d_in[17];
  float* out = (float*)d_out;
  char* ws = (char*)d_ws;

  // workspace layout (bytes); high-water ~104 MiB
  __bf16* xb    = (__bf16*)(ws + 0);           // 8 MiB (free after QKV gemm)
  __bf16* wqkvb = (__bf16*)(ws + 8388608);     // 6 MiB (free after QKV gemm)
  __bf16* wob   = (__bf16*)(ws + 14680064);    // 2 MiB (free after WO gemm)
  __bf16* w1b   = (__bf16*)(ws + 16777216);    // 8 MiB
  __bf16* w2b   = (__bf16*)(ws + 25165824);    // 8 MiB
  __bf16* qbuf  = (__bf16*)(ws + 33554432);    // 8 MiB [B*H,S,64]
  __bf16* kbuf  = (__bf16*)(ws + 41943040);    // 8 MiB
  __bf16* vtbf  = (__bf16*)(ws + 50331648);    // 8 MiB [B*H,64,S]
  __bf16* ctxb  = (__bf16*)(ws + 58720256);    // 8 MiB [4096,1024]
  __bf16* hb    = (__bf16*)(ws + 33554432);    // 32 MiB; aliases q/k/vt/ctx (consumed)
  __bf16* r1b   = (__bf16*)(ws + 67108864);    // 8 MiB (WO bf16 out; free after LN1)
  float*  p0    = (float*)(ws + 83886080);     // 16 MiB split-K partial z=0
  __bf16* tb    = (__bf16*)(ws + 100663296);   // 8 MiB (LN1 bf16 out; LN2 residual)
  float*  p1    = (float*)(ws + 0);            // 16 MiB split-K partial z=1 (aliases consumed xb/wqkvb/wob)

  const int MSD = BB * SS;  // 4096

  cvt_all_kernel<<<8192, 256, 0, stream>>>(x, wq, wk, wv, wo, w1, w2, xb, wqkvb, wob, w1b, w2b);

  // fused QKV (wide 128x256): N=3072, grid (12,32)=384 blocks
  gemm_wide<4><<<dim3(12, 32), 512, 0, stream>>>(xb, wqkvb, bq, bk, bv, (const float*)vtbf,
                                                 qbuf, kbuf, MSD, 3072, DD, 0, 0.18033688f);

  attn_kernel<<<BB * HH * (SS / 128), 256, 0, stream>>>(qbuf, kbuf, vtbf, mask, ctxb);

  // WO: r1b = bf16(ctx*wo^T + bo + x)  (128^2 kernel: full-grid coverage)
  gemm_wo<6><<<dim3(8, 32), 256, 0, stream>>>(ctxb, wob, bo, x, r1b, MSD, DD, DD);
  // LN1: tb = LN(r1b)
  ln_bf16_kernel<<<MSD, 256, 0, stream>>>(r1b, ln1g, ln1b, tb);

  // FFN1 (wide): hb = relu(tb*w1^T + b1), grid (16,32)=512 blocks
  gemm_wide<3><<<dim3(16, 32), 512, 0, stream>>>(tb, w1b, b1, nullptr, nullptr, nullptr,
                                                 hb, nullptr, MSD, FFN, DD, 0, 1.0f);

  // FFN2 split-K=2 (wide): p0/p1 = hb*w2^T partials, grid (4,32,2)=256 blocks
  gemm_wide<5><<<dim3(4, 32, 2), 512, 0, stream>>>(hb, w2b, nullptr, nullptr, nullptr, nullptr,
                                                   p0, p1, MSD, DD, FFN, 2048, 1.0f);
  // LN2 fused with reduce: out = LN(p0+p1+b2+tb) * mask
  ln2_fused_kernel<<<MSD, 256, 0, stream>>>(p0, p1, b2, tb, ln2g, ln2b, mask, out);
}

// Round 17
// 231.795 us; speedup vs baseline: 1.0461x; 1.0461x over previous
//
#include <hip/hip_runtime.h>

typedef __bf16 bf16x8 __attribute__((ext_vector_type(8)));
typedef __bf16 bf16x4 __attribute__((ext_vector_type(4)));
typedef float f32x4 __attribute__((ext_vector_type(4)));
typedef float f32x16 __attribute__((ext_vector_type(16)));

#define BB 4
#define SS 1024
#define DD 1024
#define HH 16
#define DHH 64
#define FFN 4096

__device__ __forceinline__ void gload_lds16(const void* g, void* lds) {
  __builtin_amdgcn_global_load_lds(
      (const __attribute__((address_space(1))) unsigned int*)g,
      (__attribute__((address_space(3))) unsigned int*)lds, 16, 0, 0);
}

// One-shot fp32->bf16 conversion of all inputs. Chunk = 8 elems, 2097152 chunks.
__global__ __launch_bounds__(256) void cvt_all_kernel(
    const float* __restrict__ x, const float* __restrict__ wq, const float* __restrict__ wk,
    const float* __restrict__ wv, const float* __restrict__ wo, const float* __restrict__ w1,
    const float* __restrict__ w2, __bf16* __restrict__ xb, __bf16* __restrict__ wqkvb,
    __bf16* __restrict__ wob, __bf16* __restrict__ w1b, __bf16* __restrict__ w2b)
{
  int i = blockIdx.x * 256 + threadIdx.x;   // chunk index
  const float* src; __bf16* dst; int off;
  if (i < 524288)       { src = x;  dst = xb;              off = i; }
  else if (i < 655360)  { src = wq; dst = wqkvb;           off = i - 524288; }
  else if (i < 786432)  { src = wk; dst = wqkvb + 1048576; off = i - 655360; }
  else if (i < 917504)  { src = wv; dst = wqkvb + 2097152; off = i - 786432; }
  else if (i < 1048576) { src = wo; dst = wob;             off = i - 917504; }
  else if (i < 1572864) { src = w1; dst = w1b;             off = i - 1048576; }
  else                  { src = w2; dst = w2b;             off = i - 1572864; }
  float4 a = *(const float4*)(src + off * 8);
  float4 b = *(const float4*)(src + off * 8 + 4);
  bf16x8 v;
  v[0] = (__bf16)a.x; v[1] = (__bf16)a.y; v[2] = (__bf16)a.z; v[3] = (__bf16)a.w;
  v[4] = (__bf16)b.x; v[5] = (__bf16)b.y; v[6] = (__bf16)b.z; v[7] = (__bf16)b.w;
  *(bf16x8*)(dst + off * 8) = v;
}

// 2-phase 128x128 GEMM, BK=32 (best-measured config: 32 KiB LDS, 4 blocks/CU).
// MODE 3: out bf16 = relu(acc+bias)
// MODE 4: fused QKV (N=3072): Q,K -> [B,H,S,DH]; V -> [B,H,DH,S] (via res ptr)
// MODE 5: split-K partial f32 via blockIdx.z
// MODE 6: out bf16 = acc+bias+res(f32)      (WO + residual, bf16 output)
template<int MODE>
__global__ __launch_bounds__(256, 2) void gemm_bt(
    const __bf16* __restrict__ A, const __bf16* __restrict__ Bw,
    const float* __restrict__ bias, const float* __restrict__ bias1, const float* __restrict__ bias2,
    const float* __restrict__ res, void* __restrict__ outp, void* __restrict__ out1,
    int M, int N, int K, int kLen, float scale)
{
  __shared__ __bf16 As[2][128 * 32];
  __shared__ __bf16 Bs[2][128 * 32];
  const int tid = threadIdx.x;
  const int wid = tid >> 6;
  const int lane = tid & 63;
  const int lr = lane & 15;
  const int lg = lane >> 4;

  const int gx = gridDim.x;
  const int nwg = gx * gridDim.y;
  const int wg = blockIdx.y * gx + blockIdx.x;
  const int swz = (wg & 7) * (nwg >> 3) + (wg >> 3);
  const int bm = (swz / gx) * 128;
  const int bn = (swz % gx) * 128;

  const int wm = (wid >> 1) * 64;
  const int wn = (wid & 1) * 64;

  int kBeg = 0, nk = K >> 5;
  if constexpr (MODE == 5) { kBeg = blockIdx.z * kLen; nk = kLen >> 5; }

  const int off = tid * 16;
  const int srow = off >> 6;
  const int scol = (off & 63) >> 1;
  const __bf16* gA0 = A + (size_t)(bm + srow) * K + kBeg + scol;
  const __bf16* gA1 = A + (size_t)(bm + 64 + srow) * K + kBeg + scol;
  const __bf16* gB0 = Bw + (size_t)(bn + srow) * K + kBeg + scol;
  const __bf16* gB1 = Bw + (size_t)(bn + 64 + srow) * K + kBeg + scol;
  char* lA = (char*)&As[0][0] + wid * 1024;
  char* lB = (char*)&Bs[0][0] + wid * 1024;

  f32x4 acc[4][4] = {};

#define STAGE(buf, kk) do { \
    gload_lds16(gA0 + (kk), lA + (buf) * 8192); \
    gload_lds16(gA1 + (kk), lA + (buf) * 8192 + 4096); \
    gload_lds16(gB0 + (kk), lB + (buf) * 8192); \
    gload_lds16(gB1 + (kk), lB + (buf) * 8192 + 4096); \
  } while (0)

  STAGE(0, 0);
  __syncthreads();
  for (int t = 0; t < nk; ++t) {
    const int cur = t & 1;
    if (t + 1 < nk) STAGE(cur ^ 1, (t + 1) << 5);
    bf16x8 af[4], bv[4];
#pragma unroll
    for (int i = 0; i < 4; ++i)
      af[i] = *(const bf16x8*)&As[cur][(wm + i * 16 + lr) * 32 + lg * 8];
#pragma unroll
    for (int i = 0; i < 4; ++i)
      bv[i] = *(const bf16x8*)&Bs[cur][(wn + i * 16 + lr) * 32 + lg * 8];
#pragma unroll
    for (int i = 0; i < 4; ++i)
#pragma unroll
      for (int j = 0; j < 4; ++j)
        acc[i][j] = __builtin_amdgcn_mfma_f32_16x16x32_bf16(af[i], bv[j], acc[i][j], 0, 0, 0);
    __syncthreads();
  }
#undef STAGE

  // epilogue: C/D layout col=lane&15, row=(lane>>4)*4+r  [m89-verified]
#pragma unroll
  for (int i = 0; i < 4; ++i) {
#pragma unroll
    for (int j = 0; j < 4; ++j) {
#pragma unroll
      for (int r = 0; r < 4; ++r) {
        int row = bm + wm + i * 16 + lg * 4 + r;
        int col = bn + wn + j * 16 + lr;
        float v = acc[i][j][r];
        if constexpr (MODE == 3) {
          float t2 = v + bias[col];
          ((__bf16*)outp)[(size_t)row * N + col] = (__bf16)fmaxf(t2, 0.f);
        } else if constexpr (MODE == 4) {
          int region = col >> 10;        // 0=Q 1=K 2=V (uniform per block)
          int col_ = col & 1023;
          int b_ = row >> 10, s_ = row & 1023;
          int h_ = col_ >> 6, d_ = col_ & 63;
          if (region == 0) {
            float v2 = (v + bias[col_]) * scale;   // log2e/8
            ((__bf16*)outp)[(((size_t)(b_ * HH + h_) * SS) + s_) * DHH + d_] = (__bf16)v2;
          } else if (region == 1) {
            float v2 = v + bias1[col_];
            ((__bf16*)out1)[(((size_t)(b_ * HH + h_) * SS) + s_) * DHH + d_] = (__bf16)v2;
          } else {
            float v2 = v + bias2[col_];
            ((__bf16*)res)[(((size_t)(b_ * HH + h_) * DHH) + d_) * SS + s_] = (__bf16)v2;
          }
        } else if constexpr (MODE == 5) {
          float* dst = blockIdx.z ? (float*)out1 : (float*)outp;
          dst[(size_t)row * N + col] = v;
        } else if constexpr (MODE == 6) {
          size_t idx = (size_t)row * N + col;
          ((__bf16*)outp)[idx] = (__bf16)(v + bias[col] + res[idx]);
        }
      }
    }
  }
}

// Flash attention: LDS-staged double-buffered K/V, 32x32x16 MFMA,
// fixed-max softmax, XOR slot-swizzle.
__global__ __launch_bounds__(256, 2) void attn_kernel(
    const __bf16* __restrict__ q, const __bf16* __restrict__ k,
    const __bf16* __restrict__ vt, const int* __restrict__ mask,
    __bf16* __restrict__ ctx)
{
  const int nwg = gridDim.x;          // 512
  const int wg = blockIdx.x;
  const int swzb = (wg & 7) * (nwg >> 3) + (wg >> 3);
  const int bh = swzb >> 3;
  const int qb = (swzb & 7) << 7;
  const int b = bh >> 4;

  const int tid = threadIdx.x, wid = tid >> 6, lane = tid & 63;
  const int ln = lane & 31, hi = lane >> 5;

  __shared__ __bf16 Kt[2][64 * 64];
  __shared__ __bf16 Vt[2][64 * 64];
  __shared__ __bf16 Pt[4][32 * 64];
  __shared__ float mmulLds[SS];

  {
    const int* mrow = mask + b * SS;
    int c = tid * 4;
    float4 mm;
    mm.x = (float)(mrow[c + 0] != 0);
    mm.y = (float)(mrow[c + 1] != 0);
    mm.z = (float)(mrow[c + 2] != 0);
    mm.w = (float)(mrow[c + 3] != 0);
    ((float4*)mmulLds)[tid] = mm;
  }

  const __bf16* qh = q + (size_t)bh * SS * DHH;
  const __bf16* kh = k + (size_t)bh * SS * DHH;
  const __bf16* vh = vt + (size_t)bh * DHH * SS;

  const int qw = qb + wid * 32;
  bf16x8 qf[4];
#pragma unroll
  for (int s = 0; s < 4; ++s)
    qf[s] = *(const bf16x8*)&qh[(size_t)(qw + ln) * DHH + s * 16 + hi * 8];

  const int srow = tid >> 3;
  const int ps = tid & 7;
  const int sw0 = (srow ^ (srow >> 3)) & 7;
  const int r1 = srow + 32;
  const int sw1 = (r1 ^ (r1 >> 3)) & 7;
  const __bf16* kS0 = kh + (size_t)srow * DHH + ((ps ^ sw0) * 8);
  const __bf16* kS1 = kh + (size_t)r1 * DHH + ((ps ^ sw1) * 8);
  const __bf16* vS0 = vh + (size_t)srow * SS + ((ps ^ sw0) * 8);
  const __bf16* vS1 = vh + (size_t)r1 * SS + ((ps ^ sw1) * 8);

#define ASTAGE(bufi, kb_) do { \
    gload_lds16(kS0 + (size_t)(kb_) * DHH, (char*)&Kt[bufi][0] + wid * 1024); \
    gload_lds16(kS1 + (size_t)(kb_) * DHH, (char*)&Kt[bufi][0] + wid * 1024 + 4096); \
    gload_lds16(vS0 + (kb_), (char*)&Vt[bufi][0] + wid * 1024); \
    gload_lds16(vS1 + (kb_), (char*)&Vt[bufi][0] + wid * 1024 + 4096); \
  } while (0)

  char* Pw = (char*)&Pt[wid][0];
  const int swA = (ln ^ (ln >> 3)) & 7;
  const int swB = swA ^ 4;

  f32x16 o0 = {}, o1 = {};
  float l[16];
#pragma unroll
  for (int r = 0; r < 16; ++r) l[r] = 0.f;

  ASTAGE(0, 0);
  __syncthreads();

#pragma unroll 1
  for (int t = 0; t < SS / 64; ++t) {
    const int cur = t & 1;
    const int kb = t * 64;
    if (t + 1 < SS / 64) ASTAGE(cur ^ 1, kb + 64);

    const char* Kc = (const char*)&Kt[cur][0];
    const char* Vc = (const char*)&Vt[cur][0];

    f32x16 sc0 = {}, sc1 = {};
#pragma unroll
    for (int s = 0; s < 4; ++s) {
      bf16x8 kb0 = *(const bf16x8*)(Kc + ln * 128 + (((s * 2 + hi) ^ swA) << 4));
      bf16x8 kb1 = *(const bf16x8*)(Kc + (32 + ln) * 128 + (((s * 2 + hi) ^ swB) << 4));
      sc0 = __builtin_amdgcn_mfma_f32_32x32x16_bf16(qf[s], kb0, sc0, 0, 0, 0);
      sc1 = __builtin_amdgcn_mfma_f32_32x32x16_bf16(qf[s], kb1, sc1, 0, 0, 0);
    }

    float mm0 = mmulLds[kb + ln];
    float mm1 = mmulLds[kb + 32 + ln];
#pragma unroll
    for (int r = 0; r < 16; ++r) {
      float p0 = exp2f(sc0[r] - 23.0831207f) * mm0;
      float p1 = exp2f(sc1[r] - 23.0831207f) * mm1;
      l[r] += p0 + p1;
      int qrow = (r & 3) + 8 * (r >> 2) + 4 * hi;
      int swq = (qrow ^ (qrow >> 3)) & 7;
      *(__bf16*)(Pw + qrow * 128 + ((((ln >> 3) + 0) ^ swq) << 4) + (ln & 7) * 2) = (__bf16)p0;
      *(__bf16*)(Pw + qrow * 128 + ((((ln >> 3) + 4) ^ swq) << 4) + (ln & 7) * 2) = (__bf16)p1;
    }

#pragma unroll
    for (int ks = 0; ks < 4; ++ks) {
      bf16x8 pa = *(const bf16x8*)(Pw + ln * 128 + (((ks * 2 + hi) ^ swA) << 4));
      bf16x8 vb0 = *(const bf16x8*)(Vc + ln * 128 + (((ks * 2 + hi) ^ swA) << 4));
      bf16x8 vb1 = *(const bf16x8*)(Vc + (32 + ln) * 128 + (((ks * 2 + hi) ^ swB) << 4));
      o0 = __builtin_amdgcn_mfma_f32_32x32x16_bf16(pa, vb0, o0, 0, 0, 0);
      o1 = __builtin_amdgcn_mfma_f32_32x32x16_bf16(pa, vb1, o1, 0, 0, 0);
    }
    __syncthreads();
  }
#undef ASTAGE

#pragma unroll
  for (int r = 0; r < 16; ++r) {
#pragma unroll
    for (int off = 1; off < 32; off <<= 1) l[r] += __shfl_xor(l[r], off);
  }

#pragma unroll
  for (int r = 0; r < 16; ++r) {
    float inv = l[r] > 0.f ? 1.f / l[r] : 0.f;
    int qrow = (r & 3) + 8 * (r >> 2) + 4 * hi;
    size_t base = ((size_t)b * SS + qw + qrow) * DD + (size_t)(bh & 15) * DHH;
    ctx[base + ln] = (__bf16)(o0[r] * inv);
    ctx[base + 32 + ln] = (__bf16)(o1[r] * inv);
  }
}

// LayerNorm over D=1024, bf16 input, bf16 output only (tb doubles as LN2 residual)
__global__ __launch_bounds__(256) void ln_bf16_kernel(
    const __bf16* __restrict__ in, const float* __restrict__ g, const float* __restrict__ b,
    __bf16* __restrict__ out16)
{
  int row = blockIdx.x;
  int tid = threadIdx.x;
  int wid = tid >> 6, lane = tid & 63;
  bf16x4 raw = ((const bf16x4*)(in + (size_t)row * DD))[tid];
  float4 v;
  v.x = (float)raw[0]; v.y = (float)raw[1]; v.z = (float)raw[2]; v.w = (float)raw[3];
  float s = v.x + v.y + v.z + v.w;
  float sq = v.x * v.x + v.y * v.y + v.z * v.z + v.w * v.w;
#pragma unroll
  for (int o = 1; o < 64; o <<= 1) { s += __shfl_xor(s, o); sq += __shfl_xor(sq, o); }
  __shared__ float red[8];
  if (lane == 0) { red[wid] = s; red[4 + wid] = sq; }
  __syncthreads();
  s = red[0] + red[1] + red[2] + red[3];
  sq = red[4] + red[5] + red[6] + red[7];
  float mean = s * (1.f / DD);
  float var = sq * (1.f / DD) - mean * mean;
  float rstd = rsqrtf(var + 1e-5f);
  float4 gg = ((const float4*)g)[tid];
  float4 bb = ((const float4*)b)[tid];
  bf16x4 w;
  w[0] = (__bf16)((v.x - mean) * rstd * gg.x + bb.x);
  w[1] = (__bf16)((v.y - mean) * rstd * gg.y + bb.y);
  w[2] = (__bf16)((v.z - mean) * rstd * gg.z + bb.z);
  w[3] = (__bf16)((v.w - mean) * rstd * gg.w + bb.w);
  *(bf16x4*)(out16 + (size_t)row * DD + tid * 4) = w;
}

// LN2 fused with split-K reduce: v = p0 + p1 + bias(b2) + res(tb bf16); LN; mask
__global__ __launch_bounds__(256) void ln2_fused_kernel(
    const float* __restrict__ p0, const float* __restrict__ p1, const float* __restrict__ bias,
    const __bf16* __restrict__ res, const float* __restrict__ g, const float* __restrict__ b,
    const int* __restrict__ mask, float* __restrict__ out)
{
  int row = blockIdx.x;
  int tid = threadIdx.x;
  int wid = tid >> 6, lane = tid & 63;
  size_t base = (size_t)row * DD;
  float4 a0 = ((const float4*)(p0 + base))[tid];
  float4 a1 = ((const float4*)(p1 + base))[tid];
  bf16x4 rw = ((const bf16x4*)(res + base))[tid];
  float4 bs = ((const float4*)bias)[tid];
  float4 v;
  v.x = a0.x + a1.x + (float)rw[0] + bs.x;
  v.y = a0.y + a1.y + (float)rw[1] + bs.y;
  v.z = a0.z + a1.z + (float)rw[2] + bs.z;
  v.w = a0.w + a1.w + (float)rw[3] + bs.w;
  float s = v.x + v.y + v.z + v.w;
  float sq = v.x * v.x + v.y * v.y + v.z * v.z + v.w * v.w;
#pragma unroll
  for (int o = 1; o < 64; o <<= 1) { s += __shfl_xor(s, o); sq += __shfl_xor(sq, o); }
  __shared__ float red[8];
  if (lane == 0) { red[wid] = s; red[4 + wid] = sq; }
  __syncthreads();
  s = red[0] + red[1] + red[2] + red[3];
  sq = red[4] + red[5] + red[6] + red[7];
  float mean = s * (1.f / DD);
  float var = sq * (1.f / DD) - mean * mean;
  float rstd = rsqrtf(var + 1e-5f);
  float4 gg = ((const float4*)g)[tid];
  float4 bb = ((const float4*)b)[tid];
  float mk = (float)mask[row];
  float4 o;
  o.x = ((v.x - mean) * rstd * gg.x + bb.x) * mk;
  o.y = ((v.y - mean) * rstd * gg.y + bb.y) * mk;
  o.z = ((v.z - mean) * rstd * gg.z + bb.z) * mk;
  o.w = ((v.w - mean) * rstd * gg.w + bb.w) * mk;
  ((float4*)(out + base))[tid] = o;
}

extern "C" void kernel_launch(void* const* d_in, const int* in_sizes, int n_in,
                              void* d_out, int out_size, void* d_ws, size_t ws_size,
                              hipStream_t stream) {
  const float* x    = (const float*)d_in[0];
  const int*  mask  = (const int*)d_in[1];
  const float* wq   = (const float*)d_in[2];
  const float* bq   = (const float*)d_in[3];
  const float* wk   = (const float*)d_in[4];
  const float* bk   = (const float*)d_in[5];
  const float* wv   = (const float*)d_in[6];
  const float* bv   = (const float*)d_in[7];
  const float* wo   = (const float*)d_in[8];
  const float* bo   = (const float*)d_in[9];
  const float* ln1g = (const float*)d_in[10];
  const float* ln1b = (const float*)d_in[11];
  const float* w1   = (const float*)d_in[12];
  const float* b1   = (const float*)d_in[13];
  const float* w2   = (const float*)d_in[14];
  const float* b2   = (const float*)d_in[15];
  const float* ln2g = (const float*)d_in[16];
  const float* ln2b = (const float*)d_in[17];
  float* out = (float*)d_out;
  char* ws = (char*)d_ws;

  // workspace layout (bytes); high-water ~104 MiB
  __bf16* xb    = (__bf16*)(ws + 0);           // 8 MiB (free after QKV gemm)
  __bf16* wqkvb = (__bf16*)(ws + 8388608);     // 6 MiB (free after QKV gemm)
  __bf16* wob   = (__bf16*)(ws + 14680064);    // 2 MiB (free after WO gemm)
  __bf16* w1b   = (__bf16*)(ws + 16777216);    // 8 MiB
  __bf16* w2b   = (__bf16*)(ws + 25165824);    // 8 MiB
  __bf16* qbuf  = (__bf16*)(ws + 33554432);    // 8 MiB [B*H,S,64]
  __bf16* kbuf  = (__bf16*)(ws + 41943040);    // 8 MiB
  __bf16* vtbf  = (__bf16*)(ws + 50331648);    // 8 MiB [B*H,64,S]
  __bf16* ctxb  = (__bf16*)(ws + 58720256);    // 8 MiB [4096,1024]
  __bf16* hb    = (__bf16*)(ws + 33554432);    // 32 MiB; aliases q/k/vt/ctx (consumed)
  __bf16* r1b   = (__bf16*)(ws + 67108864);    // 8 MiB (WO bf16 out; free after LN1)
  float*  p0    = (float*)(ws + 83886080);     // 16 MiB split-K partial z=0
  __bf16* tb    = (__bf16*)(ws + 100663296);   // 8 MiB (LN1 bf16 out; LN2 residual)
  float*  p1    = (float*)(ws + 0);            // 16 MiB split-K partial z=1 (aliases consumed xb/wqkvb/wob)

  const int MSD = BB * SS;  // 4096

  cvt_all_kernel<<<8192, 256, 0, stream>>>(x, wq, wk, wv, wo, w1, w2, xb, wqkvb, wob, w1b, w2b);

  // fused QKV (2-phase BK=32): N=3072, grid (24,32)=768 blocks
  gemm_bt<4><<<dim3(24, 32), 256, 0, stream>>>(xb, wqkvb, bq, bk, bv, (const float*)vtbf,
                                               qbuf, kbuf, MSD, 3072, DD, 0, 0.18033688f);

  attn_kernel<<<BB * HH * (SS / 128), 256, 0, stream>>>(qbuf, kbuf, vtbf, mask, ctxb);

  // WO: r1b = bf16(ctx*wo^T + bo + x)
  gemm_bt<6><<<dim3(8, 32), 256, 0, stream>>>(ctxb, wob, bo, nullptr, nullptr, x,
                                              r1b, nullptr, MSD, DD, DD, 0, 1.0f);
  // LN1: tb = LN(r1b)  (bf16 in, bf16 out; tb also serves as LN2 residual)
  ln_bf16_kernel<<<MSD, 256, 0, stream>>>(r1b, ln1g, ln1b, tb);

  // FFN1 (2-phase BK=32): hb = relu(tb*w1^T + b1)
  gemm_bt<3><<<dim3(32, 32), 256, 0, stream>>>(tb, w1b, b1, nullptr, nullptr, nullptr,
                                               hb, nullptr, MSD, FFN, DD, 0, 1.0f);

  // FFN2 split-K=2: p0/p1 = hb*w2^T partials (K halves of 2048)
  gemm_bt<5><<<dim3(8, 32, 2), 256, 0, stream>>>(hb, w2b, nullptr, nullptr, nullptr, nullptr,
                                                 p0, p1, MSD, DD, FFN, 2048, 1.0f);
  // LN2 fused with reduce: out = LN(p0+p1+b2+tb) * mask
  ln2_fused_kernel<<<MSD, 256, 0, stream>>>(p0, p1, b2, tb, ln2g, ln2b, mask, out);
}